// Round 1
// baseline (18432.555 us; speedup 1.0000x reference)
//
#include <hip/hip_runtime.h>

#define BATCH 65536
#define DIN   256
#define DHID  512
#define BM    64
#define APAD  264   // 256 + 8 bf16 elems -> row stride 528B, 2-way bank alias (free)
#define HPAD  136   // 128 + 8
#define NSTEPS 8

typedef __attribute__((ext_vector_type(8))) short short8;
typedef __attribute__((ext_vector_type(4))) float f32x4;

__device__ __forceinline__ unsigned short f2bf(float f){
  union { float f; unsigned u; } v; v.f = f;
  unsigned u = v.u;
  unsigned r = (u + 0x7FFFu + ((u >> 16) & 1u)) >> 16;   // RN-even
  return (unsigned short)r;
}
__device__ __forceinline__ float bf2f(unsigned short h){
  union { float f; unsigned u; } v; v.u = ((unsigned)h) << 16; return v.f;
}
__device__ __forceinline__ float tanh_fast(float x){
  // 1 - 2/(exp(2x)+1); exact at +-inf saturation, ~1e-6 abs error
  float e = __expf(2.0f * x);
  return 1.0f - 2.0f / (e + 1.0f);
}

// Split + transpose weights once per launch: W1[256][512] -> W1T hi/lo [512][256],
// W2[512][256] -> W2T hi/lo [256][512]. Both have 131072 elements.
__global__ void prep_weights(const float* __restrict__ W1, const float* __restrict__ W2,
                             unsigned short* __restrict__ W1h, unsigned short* __restrict__ W1l,
                             unsigned short* __restrict__ W2h, unsigned short* __restrict__ W2l){
  int idx = blockIdx.x * blockDim.x + threadIdx.x;
  if (idx >= DIN * DHID) return;
  {
    int k = idx / DHID, n = idx % DHID;
    float v = W1[idx];
    unsigned short h = f2bf(v);
    W1h[n * DIN + k] = h;
    W1l[n * DIN + k] = f2bf(v - bf2f(h));
  }
  {
    int k = idx / DIN, n = idx % DIN;
    float v = W2[idx];
    unsigned short h = f2bf(v);
    W2h[n * DHID + k] = h;
    W2l[n * DHID + k] = f2bf(v - bf2f(h));
  }
}

__global__ void copy_f32(const float* __restrict__ src, float* __restrict__ dst, int n4){
  int i = blockIdx.x * blockDim.x + threadIdx.x;
  int stride = gridDim.x * blockDim.x;
  for (; i < n4; i += stride)
    reinterpret_cast<float4*>(dst)[i] = reinterpret_cast<const float4*>(src)[i];
}

// Fused f(y) = tanh(y W1 + b1) W2 + b2 with RK4 epilogue.
// MODE 1: Tout = Yin + cT*F ; Acc  = Yin + cA*F      (k1)
// MODE 2: Tout = Yin + cT*F ; Acc += cA*F            (k2, k3)
// MODE 3: Tout = Acc + cA*F                          (k4 -> y_new)
template<int MODE>
__global__ __launch_bounds__(512, 2)
void feval(const float* __restrict__ Ain, const float* __restrict__ Yin,
           float* __restrict__ Acc, float* __restrict__ Tout,
           const unsigned short* __restrict__ W1h, const unsigned short* __restrict__ W1l,
           const unsigned short* __restrict__ W2h, const unsigned short* __restrict__ W2l,
           const float* __restrict__ b1, const float* __restrict__ b2,
           float cT, float cA)
{
  __shared__ unsigned short Ah[BM * APAD];
  __shared__ unsigned short Al[BM * APAD];
  __shared__ unsigned short Hh[BM * HPAD];
  __shared__ unsigned short Hl[BM * HPAD];

  const int tid  = threadIdx.x;
  const int lane = tid & 63;
  const int wid  = tid >> 6;     // 0..7
  const int wr   = wid >> 1;     // 0..3 : 16-row slice
  const int wc   = wid & 1;      // 0..1 : 128-col slice of output
  const int l15  = lane & 15;
  const int l4   = lane >> 4;    // 0..3
  const size_t r0 = (size_t)blockIdx.x * BM;

  // ---- stage A tile (64x256 f32 -> hi/lo bf16 in LDS) ----
  #pragma unroll
  for (int j = 0; j < 8; ++j){
    int idx = tid + j * 512;           // 0..4095 covers 64 rows x 64 float4
    int row = idx >> 6;
    int c4  = idx & 63;
    float4 v = *reinterpret_cast<const float4*>(Ain + (r0 + row) * DIN + c4 * 4);
    float fv[4] = {v.x, v.y, v.z, v.w};
    unsigned long long ph = 0ull, pl = 0ull;
    #pragma unroll
    for (int q = 0; q < 4; ++q){
      unsigned short h = f2bf(fv[q]);
      unsigned short l = f2bf(fv[q] - bf2f(h));
      ph |= ((unsigned long long)h) << (16 * q);
      pl |= ((unsigned long long)l) << (16 * q);
    }
    int base = row * APAD + c4 * 4;
    *reinterpret_cast<unsigned long long*>(&Ah[base]) = ph;
    *reinterpret_cast<unsigned long long*>(&Al[base]) = pl;
  }
  __syncthreads();

  f32x4 acc2[8];
  #pragma unroll
  for (int i = 0; i < 8; ++i) acc2[i] = (f32x4){0.f, 0.f, 0.f, 0.f};

  const int arow = wr * 16 + l15;

  for (int ch = 0; ch < 4; ++ch){
    // ---- GEMM1 chunk: U = A * W1[:, ch*128 + wc*64 .. +64] ----
    f32x4 acc1[4];
    #pragma unroll
    for (int i = 0; i < 4; ++i) acc1[i] = (f32x4){0.f, 0.f, 0.f, 0.f};

    #pragma unroll
    for (int ks = 0; ks < 8; ++ks){
      int aoff = arow * APAD + ks * 32 + l4 * 8;
      short8 ahf = *reinterpret_cast<const short8*>(&Ah[aoff]);
      short8 alf = *reinterpret_cast<const short8*>(&Al[aoff]);
      #pragma unroll
      for (int nt = 0; nt < 4; ++nt){
        int ncol = ch * 128 + wc * 64 + nt * 16 + l15;
        int boff = ncol * DIN + ks * 32 + l4 * 8;
        short8 bh = *reinterpret_cast<const short8*>(W1h + boff);
        short8 bl = *reinterpret_cast<const short8*>(W1l + boff);
        acc1[nt] = __builtin_amdgcn_mfma_f32_16x16x32_bf16(ahf, bh, acc1[nt], 0, 0, 0);
        acc1[nt] = __builtin_amdgcn_mfma_f32_16x16x32_bf16(ahf, bl, acc1[nt], 0, 0, 0);
        acc1[nt] = __builtin_amdgcn_mfma_f32_16x16x32_bf16(alf, bh, acc1[nt], 0, 0, 0);
      }
    }

    __syncthreads();   // previous chunk's H readers done
    // ---- bias + tanh + split -> H chunk in LDS ----
    #pragma unroll
    for (int nt = 0; nt < 4; ++nt){
      int colL = wc * 64 + nt * 16 + l15;
      float bias = b1[ch * 128 + colL];
      #pragma unroll
      for (int r = 0; r < 4; ++r){
        int rowL = wr * 16 + l4 * 4 + r;
        float t = tanh_fast(acc1[nt][r] + bias);
        unsigned short th = f2bf(t);
        Hh[rowL * HPAD + colL] = th;
        Hl[rowL * HPAD + colL] = f2bf(t - bf2f(th));
      }
    }
    __syncthreads();

    // ---- GEMM2 partial: acc2 += H_chunk * W2[ch*128.. , :] ----
    #pragma unroll
    for (int ks = 0; ks < 4; ++ks){
      int hoff = arow * HPAD + ks * 32 + l4 * 8;
      short8 ahf = *reinterpret_cast<const short8*>(&Hh[hoff]);
      short8 alf = *reinterpret_cast<const short8*>(&Hl[hoff]);
      #pragma unroll
      for (int nt = 0; nt < 8; ++nt){
        int ncol = wc * 128 + nt * 16 + l15;
        int boff = ncol * DHID + ch * 128 + ks * 32 + l4 * 8;
        short8 bh = *reinterpret_cast<const short8*>(W2h + boff);
        short8 bl = *reinterpret_cast<const short8*>(W2l + boff);
        acc2[nt] = __builtin_amdgcn_mfma_f32_16x16x32_bf16(ahf, bh, acc2[nt], 0, 0, 0);
        acc2[nt] = __builtin_amdgcn_mfma_f32_16x16x32_bf16(ahf, bl, acc2[nt], 0, 0, 0);
        acc2[nt] = __builtin_amdgcn_mfma_f32_16x16x32_bf16(alf, bh, acc2[nt], 0, 0, 0);
      }
    }
  }

  // ---- epilogue: F = acc2 + b2, RK4 combine ----
  #pragma unroll
  for (int nt = 0; nt < 8; ++nt){
    int col = wc * 128 + nt * 16 + l15;
    float bias = b2[col];
    #pragma unroll
    for (int r = 0; r < 4; ++r){
      size_t row = r0 + wr * 16 + l4 * 4 + r;
      float F = acc2[nt][r] + bias;
      size_t off = row * DIN + col;
      if (MODE == 1){
        float y = Yin[off];
        Tout[off] = y + cT * F;
        Acc[off]  = y + cA * F;
      } else if (MODE == 2){
        float y = Yin[off];
        Tout[off] = y + cT * F;
        Acc[off] += cA * F;
      } else {
        Tout[off] = Acc[off] + cA * F;
      }
    }
  }
}

extern "C" void kernel_launch(void* const* d_in, const int* in_sizes, int n_in,
                              void* d_out, int out_size, void* d_ws, size_t ws_size,
                              hipStream_t stream)
{
  const float* x  = (const float*)d_in[0];
  const float* W1 = (const float*)d_in[1];
  const float* b1 = (const float*)d_in[2];
  const float* W2 = (const float*)d_in[3];
  const float* b2 = (const float*)d_in[4];
  float* out = (float*)d_out;

  char* ws = (char*)d_ws;
  unsigned short* W1h = (unsigned short*)ws;
  unsigned short* W1l = W1h + DIN * DHID;
  unsigned short* W2h = W1l + DIN * DHID;
  unsigned short* W2l = W2h + DIN * DHID;
  float* Y = (float*)(ws + (1 << 20));                 // 64 MiB state
  float* T = Y + (size_t)BATCH * DIN;                  // 64 MiB temp state
  // total ws use: 1 MiB + 128 MiB

  prep_weights<<<512, 256, 0, stream>>>(W1, W2, W1h, W1l, W2h, W2l);
  copy_f32<<<2048, 256, 0, stream>>>(x, Y, BATCH * DIN / 4);

  const float h = 1.0f / (float)NSTEPS;
  dim3 grid(BATCH / BM), block(512);
  for (int s = 0; s < NSTEPS; ++s){
    // k1
    feval<1><<<grid, block, 0, stream>>>(Y, Y, out, T, W1h, W1l, W2h, W2l, b1, b2, 0.5f * h, h / 6.0f);
    // k2
    feval<2><<<grid, block, 0, stream>>>(T, Y, out, T, W1h, W1l, W2h, W2l, b1, b2, 0.5f * h, h / 3.0f);
    // k3
    feval<2><<<grid, block, 0, stream>>>(T, Y, out, T, W1h, W1l, W2h, W2l, b1, b2, h, h / 3.0f);
    // k4 -> y_new (last step writes directly to d_out; Acc IS d_out)
    float* dst = (s == NSTEPS - 1) ? out : Y;
    feval<3><<<grid, block, 0, stream>>>(T, Y, out, dst, W1h, W1l, W2h, W2l, b1, b2, 0.0f, h / 6.0f);
  }
}